// Round 2
// 2652.850 us; speedup vs baseline: 1.2177x; 1.2177x over previous
//
#include <hip/hip_runtime.h>
#include <hip/hip_fp16.h>
#include <cstddef>
#include <cstdint>

#define NSG   8
#define NPAIR 28
#define NBLK  36                 // unique cost products: 28 cross + 8 self
#define NPT   1024
#define DIM   256
#define NROW  8192
#define LOG_N  6.9314718055994531f
#define LOG2E  1.4426950408889634f
#define LN2    0.69314718055994531f

typedef unsigned short u16;
typedef __attribute__((ext_vector_type(8))) short bfrag;   // 8 x bf16
typedef __attribute__((ext_vector_type(4))) float f32x4;

// triu_indices(8,1) pairs, then 8 self pairs
__constant__ int c_pa[NBLK] = {0,0,0,0,0,0,0,1,1,1,1,1,1,2,2,2,2,2,3,3,3,3,4,4,4,5,5,6, 0,1,2,3,4,5,6,7};
__constant__ int c_pb[NBLK] = {1,2,3,4,5,6,7,2,3,4,5,6,7,3,4,5,6,7,4,5,6,7,5,6,7,6,7,7, 0,1,2,3,4,5,6,7};

__device__ __forceinline__ float wredMax(float v) {
#pragma unroll
  for (int o = 32; o > 0; o >>= 1) v = fmaxf(v, __shfl_xor(v, o, 64));
  return v;
}
__device__ __forceinline__ float wredMin(float v) {
#pragma unroll
  for (int o = 32; o > 0; o >>= 1) v = fminf(v, __shfl_xor(v, o, 64));
  return v;
}
__device__ __forceinline__ float wredSum(float v) {
#pragma unroll
  for (int o = 32; o > 0; o >>= 1) v += __shfl_xor(v, o, 64);
  return v;
}

__device__ __forceinline__ void cvt16(float4 A, float4 B, float* c) {
  const __half2* ha = (const __half2*)&A;
  const __half2* hb = (const __half2*)&B;
#pragma unroll
  for (int i = 0; i < 4; i++) {
    float2 f = __half22float2(ha[i]);
    c[2 * i] = f.x; c[2 * i + 1] = f.y;
  }
#pragma unroll
  for (int i = 0; i < 4; i++) {
    float2 f = __half22float2(hb[i]);
    c[8 + 2 * i] = f.x; c[8 + 2 * i + 1] = f.y;
  }
}

__device__ __forceinline__ float ub(unsigned int w, int s) {
  return (float)((w >> s) & 0xffu);   // v_cvt_f32_ubyteN
}

__device__ __forceinline__ void gload_lds16(const void* g, void* l) {
  __builtin_amdgcn_global_load_lds((const __attribute__((address_space(1))) void*)g,
                                   (__attribute__((address_space(3))) void*)l, 16, 0, 0);
}

// ---- phase 0: grouping ----
__global__ void build_idx(const int* __restrict__ sg, int* __restrict__ idx, int* __restrict__ cnt) {
  int i = blockIdx.x * 256 + threadIdx.x;
  if (i >= NROW) return;
  int s = sg[i];
  int r = atomicAdd(&cnt[s], 1);
  idx[s * NPT + r] = i;
}

// gather + bf16 convert (RNE) + 0.5*||x||^2
__global__ void gather_rows(const float* __restrict__ feat, const int* __restrict__ idx,
                            u16* __restrict__ Gh, float* __restrict__ sq) {
  int row = blockIdx.x;
  int src = idx[row];
  float v = feat[(size_t)src * DIM + threadIdx.x];
  unsigned int u = __float_as_uint(v);
  unsigned int r = (u + 0x7fffu + ((u >> 16) & 1u)) >> 16;   // bf16 RNE
  Gh[(size_t)row * DIM + threadIdx.x] = (u16)r;
  float p = wredSum(v * v);
  __shared__ float ws[4];
  if ((threadIdx.x & 63) == 0) ws[threadIdx.x >> 6] = p;
  __syncthreads();
  if (threadIdx.x == 0) sq[row] = 0.5f * (ws[0] + ws[1] + ws[2] + ws[3]);
}

// ---- phase 1: cost matrices via bf16 MFMA into Ch[b] (fp16) ----
// 128x128 tile/block, 4 waves in 2x2 grid, each wave 64x64 via 4x4 16x16x32 frags.
// LDS k-major [kgroup][row][8bf16]: conflict-free ds_read_b128, linear global_load_lds dest.
__global__ __launch_bounds__(256) void cost_gemm(const u16* __restrict__ Gh,
                                                 const float* __restrict__ sq,
                                                 __half* __restrict__ Ch) {
  __shared__ __align__(16) u16 As[4][128][8];   // 8 KB
  __shared__ __align__(16) u16 Bs[4][128][8];   // 8 KB
  const int blk = blockIdx.x;
  const int b = blk >> 6, t = blk & 63;
  const int sa = c_pa[b], sb = c_pb[b];
  const int i0 = (t >> 3) << 7, j0 = (t & 7) << 7;
  const int tid = threadIdx.x;
  const int lane = tid & 63;
  const int wid = tid >> 6;
  const int wr = wid >> 1, wc = wid & 1;
  const int kq = lane >> 4, r16 = lane & 15;

  const u16* Abase = Gh + (size_t)(sa * NPT + i0) * DIM;
  const u16* Bbase = Gh + (size_t)(sb * NPT + j0) * DIM;

  // staging: linear unit u covers (g = u>>7, row = u&127); dest = u*16 bytes
  const int su0 = tid, su1 = 256 + tid;
  const int sg0 = su0 >> 7, sr0 = su0 & 127;
  const int sg1 = su1 >> 7, sr1 = su1 & 127;

  f32x4 acc[4][4];
#pragma unroll
  for (int mi = 0; mi < 4; mi++)
#pragma unroll
    for (int nj = 0; nj < 4; nj++) {
      f32x4 z = {0.f, 0.f, 0.f, 0.f};
      acc[mi][nj] = z;
    }

  for (int k0 = 0; k0 < DIM; k0 += 32) {
    __syncthreads();
    gload_lds16(Abase + (size_t)sr0 * DIM + k0 + sg0 * 8, (char*)As + su0 * 16);
    gload_lds16(Abase + (size_t)sr1 * DIM + k0 + sg1 * 8, (char*)As + su1 * 16);
    gload_lds16(Bbase + (size_t)sr0 * DIM + k0 + sg0 * 8, (char*)Bs + su0 * 16);
    gload_lds16(Bbase + (size_t)sr1 * DIM + k0 + sg1 * 8, (char*)Bs + su1 * 16);
    __syncthreads();   // compiler drains vmcnt(0) here -> LDS valid
    bfrag af[4], bf[4];
#pragma unroll
    for (int mi = 0; mi < 4; mi++)
      af[mi] = *(const bfrag*)&As[kq][wr * 64 + mi * 16 + r16][0];
#pragma unroll
    for (int nj = 0; nj < 4; nj++)
      bf[nj] = *(const bfrag*)&Bs[kq][wc * 64 + nj * 16 + r16][0];
#pragma unroll
    for (int mi = 0; mi < 4; mi++)
#pragma unroll
      for (int nj = 0; nj < 4; nj++)
        acc[mi][nj] = __builtin_amdgcn_mfma_f32_16x16x32_bf16(af[mi], bf[nj], acc[mi][nj], 0, 0, 0);
  }

  // epilogue: C/D layout col=lane&15, row=4*(lane>>4)+reg
  float4 sqa[4];
#pragma unroll
  for (int mi = 0; mi < 4; mi++)
    sqa[mi] = *(const float4*)&sq[sa * NPT + i0 + wr * 64 + mi * 16 + 4 * kq];
  float sqb[4];
#pragma unroll
  for (int nj = 0; nj < 4; nj++)
    sqb[nj] = sq[sb * NPT + j0 + wc * 64 + nj * 16 + r16];
  __half* dst = Ch + ((size_t)b << 20);
#pragma unroll
  for (int mi = 0; mi < 4; mi++) {
    const int rowb = i0 + wr * 64 + mi * 16 + 4 * kq;
#pragma unroll
    for (int r = 0; r < 4; r++) {
      const float sav = ((const float*)&sqa[mi])[r];
      __half* drow = dst + ((size_t)(rowb + r) << 10);
#pragma unroll
      for (int nj = 0; nj < 4; nj++) {
        const int col = j0 + wc * 64 + nj * 16 + r16;
        drow[col] = __float2half_rn(fmaxf(sav + sqb[nj] - acc[mi][nj][r], 0.f));
      }
    }
  }
}

// ---- phase 1b: per-row u8 quantization into C8 slot (q = 8a+b layout; diag = 9a) ----
__global__ __launch_bounds__(256) void quant_row(const __half* __restrict__ Ch,
                                                 unsigned char* __restrict__ C8,
                                                 float2* __restrict__ rowScale) {
  const int blk = blockIdx.x;
  const int b = blk >> 4, rowblk = blk & 15;
  const int sa = c_pa[b], sb = c_pb[b];
  const int q = (sa == sb) ? 9 * sa : 8 * sa + sb;
  const __half* src = Ch + ((size_t)b << 20);
  unsigned char* dst = C8 + ((size_t)q << 20);
  const int wave = threadIdx.x >> 6, lane = threadIdx.x & 63;
  for (int jj = 0; jj < 16; jj++) {
    const int row = (rowblk << 6) + (jj << 2) + wave;
    const float4* s4 = (const float4*)(src + ((size_t)row << 10) + (lane << 4));
    float c[16];
    cvt16(s4[0], s4[1], c);
    float mn = c[0], mx = c[0];
#pragma unroll
    for (int t = 1; t < 16; t++) { mn = fminf(mn, c[t]); mx = fmaxf(mx, c[t]); }
    mn = wredMin(mn);
    mx = wredMax(mx);
    const float range = mx - mn;
    const float scale = (range > 1e-6f) ? range * (1.0f / 255.0f) : 1.0f;
    const float inv = (range > 1e-6f) ? 255.0f / range : 0.0f;
    unsigned int w[4];
#pragma unroll
    for (int d = 0; d < 4; d++) {
      unsigned int u0 = min(__float2uint_rn((c[4 * d + 0] - mn) * inv), 255u);
      unsigned int u1 = min(__float2uint_rn((c[4 * d + 1] - mn) * inv), 255u);
      unsigned int u2 = min(__float2uint_rn((c[4 * d + 2] - mn) * inv), 255u);
      unsigned int u3 = min(__float2uint_rn((c[4 * d + 3] - mn) * inv), 255u);
      w[d] = u0 | (u1 << 8) | (u2 << 16) | (u3 << 24);
    }
    *(uint4*)(dst + ((size_t)row << 10) + (lane << 4)) = make_uint4(w[0], w[1], w[2], w[3]);
    if (lane == 0) rowScale[(q << 10) + row] = make_float2(mn, scale);
  }
}

// ---- phase 1c: column stats for the transposed copies ----
__global__ __launch_bounds__(256) void colminmax(const __half* __restrict__ Ch,
                                                 float4* __restrict__ pMn, float4* __restrict__ pMx) {
  const int blk = blockIdx.x;
  const int p = blk >> 3, rb = blk & 7;
  const int j0 = threadIdx.x << 2;
  const __half* src = Ch + ((size_t)p << 20) + j0;
  float mn[4] = {3.4e38f, 3.4e38f, 3.4e38f, 3.4e38f};
  float mx[4] = {-3.4e38f, -3.4e38f, -3.4e38f, -3.4e38f};
  for (int r = 0; r < 128; r++) {
    const int row = (rb << 7) + r;
    uint2 raw = *(const uint2*)(src + ((size_t)row << 10));
    const __half2* hh = (const __half2*)&raw;
    float2 f0 = __half22float2(hh[0]);
    float2 f1 = __half22float2(hh[1]);
    float v[4] = {f0.x, f0.y, f1.x, f1.y};
#pragma unroll
    for (int t = 0; t < 4; t++) { mn[t] = fminf(mn[t], v[t]); mx[t] = fmaxf(mx[t], v[t]); }
  }
  const int o = ((p << 3) + rb) * 256 + threadIdx.x;
  pMn[o] = make_float4(mn[0], mn[1], mn[2], mn[3]);
  pMx[o] = make_float4(mx[0], mx[1], mx[2], mx[3]);
}

__global__ void colreduce(const float4* __restrict__ pMn, const float4* __restrict__ pMx,
                          float2* __restrict__ rowScale) {
  const int id = blockIdx.x * 256 + threadIdx.x;   // 28*256
  const int p = id >> 8, t = id & 255;
  float4 mn = pMn[(p << 3) * 256 + t];
  float4 mx = pMx[(p << 3) * 256 + t];
  for (int rb = 1; rb < 8; rb++) {
    float4 a = pMn[((p << 3) + rb) * 256 + t];
    float4 b = pMx[((p << 3) + rb) * 256 + t];
    mn.x = fminf(mn.x, a.x); mn.y = fminf(mn.y, a.y); mn.z = fminf(mn.z, a.z); mn.w = fminf(mn.w, a.w);
    mx.x = fmaxf(mx.x, b.x); mx.y = fmaxf(mx.y, b.y); mx.z = fmaxf(mx.z, b.z); mx.w = fmaxf(mx.w, b.w);
  }
  const int qT = 8 * c_pb[p] + c_pa[p];
  float bs[4] = {mn.x, mn.y, mn.z, mn.w};
  float xs[4] = {mx.x, mx.y, mx.z, mx.w};
#pragma unroll
  for (int cc = 0; cc < 4; cc++) {
    float range = xs[cc] - bs[cc];
    float scale = (range > 1e-6f) ? range * (1.0f / 255.0f) : 1.0f;
    rowScale[(qT << 10) + (t << 2) + cc] = make_float2(bs[cc], scale);
  }
}

// ---- phase 1d: transpose + quantize into the mate slot ----
__global__ __launch_bounds__(256) void quantT(const __half* __restrict__ Ch,
                                              const float2* __restrict__ rowScale,
                                              unsigned char* __restrict__ C8) {
  __shared__ __half t[64][72];
  const int blk = blockIdx.x;            // p*256 + tile
  const int p = blk >> 8, tb = blk & 255;
  const int i0 = (tb >> 4) << 6, j0 = (tb & 15) << 6;
  const int qT = 8 * c_pb[p] + c_pa[p];
  const __half* src = Ch + ((size_t)p << 20);
  unsigned char* dst = C8 + ((size_t)qT << 20);
  const int tid = threadIdx.x;
  const int r = tid >> 2, cg = (tid & 3) << 4;
  const float4* s4 = (const float4*)(src + ((size_t)(i0 + r) << 10) + j0 + cg);
  float4 v0 = s4[0], v1 = s4[1];
  *(float4*)&t[r][cg] = v0;
  *(float4*)&t[r][cg + 8] = v1;
  __syncthreads();
  const int jr = j0 + r;                 // dest row
  const float2 sc = rowScale[(qT << 10) + jr];
  const float inv = 1.0f / sc.y;
  unsigned int w[4];
#pragma unroll
  for (int d = 0; d < 4; d++) {
    unsigned int uu[4];
#pragma unroll
    for (int e = 0; e < 4; e++) {
      float c = __half2float(t[cg + 4 * d + e][r]);
      uu[e] = min(__float2uint_rn((c - sc.x) * inv), 255u);
    }
    w[d] = uu[0] | (uu[1] << 8) | (uu[2] << 16) | (uu[3] << 24);
  }
  *(uint4*)(dst + ((size_t)jr << 10) + i0 + cg) = make_uint4(w[0], w[1], w[2], w[3]);
}

// ---- phase 2: one Sinkhorn step = 64 row-softmins over u8 C. ----
// Log2-domain refactor: b = fma(u, -rs.y*c0, h*c0); row shift rs.x cancels inside
// softmax and is reapplied at the end (error lands scaled by eps, negligible).
// Registers kept <= 64 (uv in 2 batches of 4) so launch_bounds(256,8) gives
// 8 blocks/CU -> the 2048-block grid runs in ONE occupancy round instead of two.
template <bool LSE>
__global__ __launch_bounds__(256, 8) void sink_step(
    const unsigned char* __restrict__ C8, const float2* __restrict__ rowScale,
    const float* __restrict__ pot_cur, float* __restrict__ pot_nxt,
    float eps, float csS, float cmS) {
  const int i = blockIdx.x;
  const int x = i & 7, rr = i >> 3;
  const int q = ((rr & 7) << 3) | x;     // XCD swizzle: q's low 3 bits pinned to XCD
  const int chunk = rr >> 3;
  const int mate = ((q & 7) << 3) | (q >> 3);
  const bool diag = (mate == q);
  const float cs = diag ? csS : 0.f;
  const float cm = diag ? cmS : 1.f;
  const int wave = threadIdx.x >> 6, lane = threadIdx.x & 63;
  const float c0 = LOG2E / eps;
  const float el2 = eps * LN2;
  float h[16];
  {
    const float4* hp = (const float4*)(pot_cur + (mate << 10) + (lane << 4));
    float4 h0 = hp[0], h1 = hp[1], h2 = hp[2], h3 = hp[3];
    h[0]=h0.x; h[1]=h0.y; h[2]=h0.z; h[3]=h0.w;
    h[4]=h1.x; h[5]=h1.y; h[6]=h1.z; h[7]=h1.w;
    h[8]=h2.x; h[9]=h2.y; h[10]=h2.z; h[11]=h2.w;
    h[12]=h3.x; h[13]=h3.y; h[14]=h3.z; h[15]=h3.w;
  }
  if (LSE) {
#pragma unroll
    for (int tt = 0; tt < 16; tt++) h[tt] *= c0;
  }
  const unsigned char* Cb = C8 + ((size_t)q << 20) + ((size_t)chunk << 15) + (lane << 4);
  const int rb = chunk << 5;

#pragma unroll
  for (int half = 0; half < 2; half++) {
    uint4 uv[4];
#pragma unroll
    for (int k = 0; k < 4; k++)
      uv[k] = *(const uint4*)(Cb + ((size_t)((half << 4) + (k << 2) + wave) << 10));
#pragma unroll
    for (int k = 0; k < 4; k++) {
      const int row = rb + (half << 4) + (k << 2) + wave;
      const float2 rs = rowScale[(q << 10) + row];
      const float ns = LSE ? (-rs.y) * c0 : -rs.y;
      const unsigned int w0 = uv[k].x, w1 = uv[k].y, w2 = uv[k].z, w3 = uv[k].w;
      float b[16];
      b[0]  = fmaf(ub(w0, 0),  ns, h[0]);  b[1]  = fmaf(ub(w0, 8),  ns, h[1]);
      b[2]  = fmaf(ub(w0, 16), ns, h[2]);  b[3]  = fmaf(ub(w0, 24), ns, h[3]);
      b[4]  = fmaf(ub(w1, 0),  ns, h[4]);  b[5]  = fmaf(ub(w1, 8),  ns, h[5]);
      b[6]  = fmaf(ub(w1, 16), ns, h[6]);  b[7]  = fmaf(ub(w1, 24), ns, h[7]);
      b[8]  = fmaf(ub(w2, 0),  ns, h[8]);  b[9]  = fmaf(ub(w2, 8),  ns, h[9]);
      b[10] = fmaf(ub(w2, 16), ns, h[10]); b[11] = fmaf(ub(w2, 24), ns, h[11]);
      b[12] = fmaf(ub(w3, 0),  ns, h[12]); b[13] = fmaf(ub(w3, 8),  ns, h[13]);
      b[14] = fmaf(ub(w3, 16), ns, h[14]); b[15] = fmaf(ub(w3, 24), ns, h[15]);
      float m = b[0];
#pragma unroll
      for (int tt = 1; tt < 16; tt++) m = fmaxf(m, b[tt]);
      m = wredMax(m);
      float sm;
      if (LSE) {
        float ss = 0.f;
#pragma unroll
        for (int tt = 0; tt < 16; tt++) ss += exp2f(b[tt] - m);  // max term exact 0
        ss = wredSum(ss);
        sm = rs.x - fmaf(el2, m, eps * (__logf(ss) - LOG_N));
      } else {
        sm = rs.x - m;   // softmin -> min as eps -> 0; |err| <= eps*log n
      }
      if (lane == 0)
        pot_nxt[(q << 10) + row] = cs * pot_cur[(q << 10) + row] + cm * sm;
    }
  }
}

// ---- phase 3: losses ----
__global__ void loss_pairs(const float* __restrict__ pot, float* __restrict__ out) {
  int pb = blockIdx.x;
  int si = c_pa[pb], sj = c_pb[pb];
  const float* fv = pot + ((8 * si + sj) << 10);
  const float* gv = pot + ((8 * sj + si) << 10);
  const float* sa = pot + ((9 * si) << 10);
  const float* sb = pot + ((9 * sj) << 10);
  float acc = 0.f;
  for (int t = threadIdx.x; t < NPT; t += 256)
    acc += (fv[t] - sa[t]) + (gv[t] - sb[t]);
  acc = wredSum(acc);
  __shared__ float wsm[4];
  if ((threadIdx.x & 63) == 0) wsm[threadIdx.x >> 6] = acc;
  __syncthreads();
  if (threadIdx.x == 0) out[1 + pb] = (wsm[0] + wsm[1] + wsm[2] + wsm[3]) * (1.0f / NPT);
}

__global__ void loss_total(float* __restrict__ out) {
  int t = threadIdx.x;
  float x = (t < NPAIR) ? out[1 + t] : 0.f;
  x = wredSum(x);
  if (t == 0) out[0] = x / (float)NPAIR;
}

extern "C" void kernel_launch(void* const* d_in, const int* in_sizes, int n_in,
                              void* d_out, int out_size, void* d_ws, size_t ws_size,
                              hipStream_t stream) {
  const float* feat = (const float*)d_in[0];
  const int* sg = (const int*)d_in[1];
  float* out = (float*)d_out;
  char* ws = (char*)d_ws;

  size_t o = 0;
  __half* Ch = (__half*)(ws + o); o += (size_t)NBLK * NPT * NPT * 2;      // 72 MB (fp16 staging)
  unsigned char* C8 = (unsigned char*)(ws + o); o += (size_t)64 * NPT * NPT; // 64 MB (u8, both orientations)
  float2* rowScale = (float2*)(ws + o); o += (size_t)64 * NPT * 8;        // 512 KB
  float4* pMn = (float4*)(ws + o); o += (size_t)NPAIR * 8 * 256 * 16;     // 0.9 MB
  float4* pMx = (float4*)(ws + o); o += (size_t)NPAIR * 8 * 256 * 16;
  u16* Gh  = (u16*)(ws + o); o += (size_t)NROW * DIM * 2;                 // 4.2 MB (bf16 features)
  float* sq = (float*)(ws + o); o += (size_t)NROW * 4;
  int* idx  = (int*)(ws + o); o += (size_t)NROW * 4;
  int* cnt  = (int*)(ws + o); o += 1024;
  float* pot[2];
  pot[0] = (float*)(ws + o); o += (size_t)64 * NPT * 4;
  pot[1] = (float*)(ws + o); o += (size_t)64 * NPT * 4;

  hipMemsetAsync(cnt, 0, 1024, stream);
  hipMemsetAsync(pot[0], 0, (size_t)64 * NPT * 4, stream);   // f0=g0=s0=0

  build_idx<<<NROW / 256, 256, 0, stream>>>(sg, idx, cnt);
  gather_rows<<<NROW, 256, 0, stream>>>(feat, idx, Gh, sq);
  cost_gemm<<<NBLK * 64, 256, 0, stream>>>(Gh, sq, Ch);
  quant_row<<<NBLK * 16, 256, 0, stream>>>(Ch, C8, rowScale);
  colminmax<<<NPAIR * 8, 256, 0, stream>>>(Ch, pMn, pMx);
  colreduce<<<NPAIR, 256, 0, stream>>>(pMn, pMx, rowScale);
  quantT<<<NPAIR * 256, 256, 0, stream>>>(Ch, rowScale, C8);

  // epsilon schedule (mirrors reference trace-time logic)
  float sched[256];
  int ns = 0;
  {
    double e = 256.0;
    const double ratio = 0.9 * 0.9;
    const double tgt = 1e-4 * 1e-4;
    while (e > tgt) { sched[ns++] = (float)e; e *= ratio; }
    sched[ns++] = (float)tgt;
  }
  const float epsT = sched[ns - 1];
  const float EPS_CUT = 1e-3f;   // below this, softmin==min to within eps*log(n) ~ 7e-3

  int cur = 0;
  for (int k = 0; k < ns; k++) {
    if (sched[k] >= EPS_CUT)
      sink_step<true><<<64 * 32, 256, 0, stream>>>(C8, rowScale, pot[cur], pot[1 - cur],
                                                   sched[k], 0.5f, 0.5f);
    else
      sink_step<false><<<64 * 32, 256, 0, stream>>>(C8, rowScale, pot[cur], pot[1 - cur],
                                                    sched[k], 0.5f, 0.5f);
    cur ^= 1;
  }
  // final extrapolation at eps_target (diag not blended); epsT=1e-8 -> min form
  sink_step<false><<<64 * 32, 256, 0, stream>>>(C8, rowScale, pot[cur], pot[1 - cur],
                                                epsT, 0.0f, 1.0f);
  cur ^= 1;
  loss_pairs<<<NPAIR, 256, 0, stream>>>(pot[cur], out);
  loss_total<<<1, 64, 0, stream>>>(out);
}

// Round 3
// 2636.848 us; speedup vs baseline: 1.2251x; 1.0061x over previous
//
#include <hip/hip_runtime.h>
#include <hip/hip_fp16.h>
#include <cstddef>
#include <cstdint>

#define NSG   8
#define NPAIR 28
#define NBLK  36                 // unique cost products: 28 cross + 8 self
#define NPT   1024
#define DIM   256
#define NROW  8192
#define LOG_N  6.9314718055994531f
#define LOG2E  1.4426950408889634f
#define LN2    0.69314718055994531f

typedef unsigned short u16;
typedef __attribute__((ext_vector_type(8))) short bfrag;   // 8 x bf16
typedef __attribute__((ext_vector_type(4))) float f32x4;

// triu_indices(8,1) pairs, then 8 self pairs
__constant__ int c_pa[NBLK] = {0,0,0,0,0,0,0,1,1,1,1,1,1,2,2,2,2,2,3,3,3,3,4,4,4,5,5,6, 0,1,2,3,4,5,6,7};
__constant__ int c_pb[NBLK] = {1,2,3,4,5,6,7,2,3,4,5,6,7,3,4,5,6,7,4,5,6,7,5,6,7,6,7,7, 0,1,2,3,4,5,6,7};

__device__ __forceinline__ float wredMax(float v) {
#pragma unroll
  for (int o = 32; o > 0; o >>= 1) v = fmaxf(v, __shfl_xor(v, o, 64));
  return v;
}
__device__ __forceinline__ float wredMin(float v) {
#pragma unroll
  for (int o = 32; o > 0; o >>= 1) v = fminf(v, __shfl_xor(v, o, 64));
  return v;
}
__device__ __forceinline__ float wredSum(float v) {
#pragma unroll
  for (int o = 32; o > 0; o >>= 1) v += __shfl_xor(v, o, 64);
  return v;
}

__device__ __forceinline__ void cvt16(float4 A, float4 B, float* c) {
  const __half2* ha = (const __half2*)&A;
  const __half2* hb = (const __half2*)&B;
#pragma unroll
  for (int i = 0; i < 4; i++) {
    float2 f = __half22float2(ha[i]);
    c[2 * i] = f.x; c[2 * i + 1] = f.y;
  }
#pragma unroll
  for (int i = 0; i < 4; i++) {
    float2 f = __half22float2(hb[i]);
    c[8 + 2 * i] = f.x; c[8 + 2 * i + 1] = f.y;
  }
}

__device__ __forceinline__ float ub(unsigned int w, int s) {
  return (float)((w >> s) & 0xffu);   // v_cvt_f32_ubyteN
}

__device__ __forceinline__ void gload_lds16(const void* g, void* l) {
  __builtin_amdgcn_global_load_lds((const __attribute__((address_space(1))) void*)g,
                                   (__attribute__((address_space(3))) void*)l, 16, 0, 0);
}

// ---- phase 0: grouping ----
__global__ void build_idx(const int* __restrict__ sg, int* __restrict__ idx, int* __restrict__ cnt) {
  int i = blockIdx.x * 256 + threadIdx.x;
  if (i >= NROW) return;
  int s = sg[i];
  int r = atomicAdd(&cnt[s], 1);
  idx[s * NPT + r] = i;
}

// gather + bf16 convert (RNE) + 0.5*||x||^2
__global__ void gather_rows(const float* __restrict__ feat, const int* __restrict__ idx,
                            u16* __restrict__ Gh, float* __restrict__ sq) {
  int row = blockIdx.x;
  int src = idx[row];
  float v = feat[(size_t)src * DIM + threadIdx.x];
  unsigned int u = __float_as_uint(v);
  unsigned int r = (u + 0x7fffu + ((u >> 16) & 1u)) >> 16;   // bf16 RNE
  Gh[(size_t)row * DIM + threadIdx.x] = (u16)r;
  float p = wredSum(v * v);
  __shared__ float ws[4];
  if ((threadIdx.x & 63) == 0) ws[threadIdx.x >> 6] = p;
  __syncthreads();
  if (threadIdx.x == 0) sq[row] = 0.5f * (ws[0] + ws[1] + ws[2] + ws[3]);
}

// ---- phase 1: cost matrices via bf16 MFMA into Ch[b] (fp16) ----
__global__ __launch_bounds__(256) void cost_gemm(const u16* __restrict__ Gh,
                                                 const float* __restrict__ sq,
                                                 __half* __restrict__ Ch) {
  __shared__ __align__(16) u16 As[4][128][8];   // 8 KB
  __shared__ __align__(16) u16 Bs[4][128][8];   // 8 KB
  const int blk = blockIdx.x;
  const int b = blk >> 6, t = blk & 63;
  const int sa = c_pa[b], sb = c_pb[b];
  const int i0 = (t >> 3) << 7, j0 = (t & 7) << 7;
  const int tid = threadIdx.x;
  const int lane = tid & 63;
  const int wid = tid >> 6;
  const int wr = wid >> 1, wc = wid & 1;
  const int kq = lane >> 4, r16 = lane & 15;

  const u16* Abase = Gh + (size_t)(sa * NPT + i0) * DIM;
  const u16* Bbase = Gh + (size_t)(sb * NPT + j0) * DIM;

  const int su0 = tid, su1 = 256 + tid;
  const int sg0 = su0 >> 7, sr0 = su0 & 127;
  const int sg1 = su1 >> 7, sr1 = su1 & 127;

  f32x4 acc[4][4];
#pragma unroll
  for (int mi = 0; mi < 4; mi++)
#pragma unroll
    for (int nj = 0; nj < 4; nj++) {
      f32x4 z = {0.f, 0.f, 0.f, 0.f};
      acc[mi][nj] = z;
    }

  for (int k0 = 0; k0 < DIM; k0 += 32) {
    __syncthreads();
    gload_lds16(Abase + (size_t)sr0 * DIM + k0 + sg0 * 8, (char*)As + su0 * 16);
    gload_lds16(Abase + (size_t)sr1 * DIM + k0 + sg1 * 8, (char*)As + su1 * 16);
    gload_lds16(Bbase + (size_t)sr0 * DIM + k0 + sg0 * 8, (char*)Bs + su0 * 16);
    gload_lds16(Bbase + (size_t)sr1 * DIM + k0 + sg1 * 8, (char*)Bs + su1 * 16);
    __syncthreads();
    bfrag af[4], bf[4];
#pragma unroll
    for (int mi = 0; mi < 4; mi++)
      af[mi] = *(const bfrag*)&As[kq][wr * 64 + mi * 16 + r16][0];
#pragma unroll
    for (int nj = 0; nj < 4; nj++)
      bf[nj] = *(const bfrag*)&Bs[kq][wc * 64 + nj * 16 + r16][0];
#pragma unroll
    for (int mi = 0; mi < 4; mi++)
#pragma unroll
      for (int nj = 0; nj < 4; nj++)
        acc[mi][nj] = __builtin_amdgcn_mfma_f32_16x16x32_bf16(af[mi], bf[nj], acc[mi][nj], 0, 0, 0);
  }

  float4 sqa[4];
#pragma unroll
  for (int mi = 0; mi < 4; mi++)
    sqa[mi] = *(const float4*)&sq[sa * NPT + i0 + wr * 64 + mi * 16 + 4 * kq];
  float sqb[4];
#pragma unroll
  for (int nj = 0; nj < 4; nj++)
    sqb[nj] = sq[sb * NPT + j0 + wc * 64 + nj * 16 + r16];
  __half* dst = Ch + ((size_t)b << 20);
#pragma unroll
  for (int mi = 0; mi < 4; mi++) {
    const int rowb = i0 + wr * 64 + mi * 16 + 4 * kq;
#pragma unroll
    for (int r = 0; r < 4; r++) {
      const float sav = ((const float*)&sqa[mi])[r];
      __half* drow = dst + ((size_t)(rowb + r) << 10);
#pragma unroll
      for (int nj = 0; nj < 4; nj++) {
        const int col = j0 + wc * 64 + nj * 16 + r16;
        drow[col] = __float2half_rn(fmaxf(sav + sqb[nj] - acc[mi][nj][r], 0.f));
      }
    }
  }
}

// ---- phase 1b: per-row u8 quantization into C8 slot (q = 8a+b layout; diag = 9a) ----
__global__ __launch_bounds__(256) void quant_row(const __half* __restrict__ Ch,
                                                 unsigned char* __restrict__ C8,
                                                 float2* __restrict__ rowScale) {
  const int blk = blockIdx.x;
  const int b = blk >> 4, rowblk = blk & 15;
  const int sa = c_pa[b], sb = c_pb[b];
  const int q = (sa == sb) ? 9 * sa : 8 * sa + sb;
  const __half* src = Ch + ((size_t)b << 20);
  unsigned char* dst = C8 + ((size_t)q << 20);
  const int wave = threadIdx.x >> 6, lane = threadIdx.x & 63;
  for (int jj = 0; jj < 16; jj++) {
    const int row = (rowblk << 6) + (jj << 2) + wave;
    const float4* s4 = (const float4*)(src + ((size_t)row << 10) + (lane << 4));
    float c[16];
    cvt16(s4[0], s4[1], c);
    float mn = c[0], mx = c[0];
#pragma unroll
    for (int t = 1; t < 16; t++) { mn = fminf(mn, c[t]); mx = fmaxf(mx, c[t]); }
    mn = wredMin(mn);
    mx = wredMax(mx);
    const float range = mx - mn;
    const float scale = (range > 1e-6f) ? range * (1.0f / 255.0f) : 1.0f;
    const float inv = (range > 1e-6f) ? 255.0f / range : 0.0f;
    unsigned int w[4];
#pragma unroll
    for (int d = 0; d < 4; d++) {
      unsigned int u0 = min(__float2uint_rn((c[4 * d + 0] - mn) * inv), 255u);
      unsigned int u1 = min(__float2uint_rn((c[4 * d + 1] - mn) * inv), 255u);
      unsigned int u2 = min(__float2uint_rn((c[4 * d + 2] - mn) * inv), 255u);
      unsigned int u3 = min(__float2uint_rn((c[4 * d + 3] - mn) * inv), 255u);
      w[d] = u0 | (u1 << 8) | (u2 << 16) | (u3 << 24);
    }
    *(uint4*)(dst + ((size_t)row << 10) + (lane << 4)) = make_uint4(w[0], w[1], w[2], w[3]);
    if (lane == 0) rowScale[(q << 10) + row] = make_float2(mn, scale);
  }
}

// ---- phase 1c: column stats for the transposed copies ----
__global__ __launch_bounds__(256) void colminmax(const __half* __restrict__ Ch,
                                                 float4* __restrict__ pMn, float4* __restrict__ pMx) {
  const int blk = blockIdx.x;
  const int p = blk >> 3, rb = blk & 7;
  const int j0 = threadIdx.x << 2;
  const __half* src = Ch + ((size_t)p << 20) + j0;
  float mn[4] = {3.4e38f, 3.4e38f, 3.4e38f, 3.4e38f};
  float mx[4] = {-3.4e38f, -3.4e38f, -3.4e38f, -3.4e38f};
  for (int r = 0; r < 128; r++) {
    const int row = (rb << 7) + r;
    uint2 raw = *(const uint2*)(src + ((size_t)row << 10));
    const __half2* hh = (const __half2*)&raw;
    float2 f0 = __half22float2(hh[0]);
    float2 f1 = __half22float2(hh[1]);
    float v[4] = {f0.x, f0.y, f1.x, f1.y};
#pragma unroll
    for (int t = 0; t < 4; t++) { mn[t] = fminf(mn[t], v[t]); mx[t] = fmaxf(mx[t], v[t]); }
  }
  const int o = ((p << 3) + rb) * 256 + threadIdx.x;
  pMn[o] = make_float4(mn[0], mn[1], mn[2], mn[3]);
  pMx[o] = make_float4(mx[0], mx[1], mx[2], mx[3]);
}

__global__ void colreduce(const float4* __restrict__ pMn, const float4* __restrict__ pMx,
                          float2* __restrict__ rowScale) {
  const int id = blockIdx.x * 256 + threadIdx.x;   // 28*256
  const int p = id >> 8, t = id & 255;
  float4 mn = pMn[(p << 3) * 256 + t];
  float4 mx = pMx[(p << 3) * 256 + t];
  for (int rb = 1; rb < 8; rb++) {
    float4 a = pMn[((p << 3) + rb) * 256 + t];
    float4 b = pMx[((p << 3) + rb) * 256 + t];
    mn.x = fminf(mn.x, a.x); mn.y = fminf(mn.y, a.y); mn.z = fminf(mn.z, a.z); mn.w = fminf(mn.w, a.w);
    mx.x = fmaxf(mx.x, b.x); mx.y = fmaxf(mx.y, b.y); mx.z = fmaxf(mx.z, b.z); mx.w = fmaxf(mx.w, b.w);
  }
  const int qT = 8 * c_pb[p] + c_pa[p];
  float bs[4] = {mn.x, mn.y, mn.z, mn.w};
  float xs[4] = {mx.x, mx.y, mx.z, mx.w};
#pragma unroll
  for (int cc = 0; cc < 4; cc++) {
    float range = xs[cc] - bs[cc];
    float scale = (range > 1e-6f) ? range * (1.0f / 255.0f) : 1.0f;
    rowScale[(qT << 10) + (t << 2) + cc] = make_float2(bs[cc], scale);
  }
}

// ---- phase 1d: transpose + quantize into the mate slot ----
__global__ __launch_bounds__(256) void quantT(const __half* __restrict__ Ch,
                                              const float2* __restrict__ rowScale,
                                              unsigned char* __restrict__ C8) {
  __shared__ __half t[64][72];
  const int blk = blockIdx.x;            // p*256 + tile
  const int p = blk >> 8, tb = blk & 255;
  const int i0 = (tb >> 4) << 6, j0 = (tb & 15) << 6;
  const int qT = 8 * c_pb[p] + c_pa[p];
  const __half* src = Ch + ((size_t)p << 20);
  unsigned char* dst = C8 + ((size_t)qT << 20);
  const int tid = threadIdx.x;
  const int r = tid >> 2, cg = (tid & 3) << 4;
  const float4* s4 = (const float4*)(src + ((size_t)(i0 + r) << 10) + j0 + cg);
  float4 v0 = s4[0], v1 = s4[1];
  *(float4*)&t[r][cg] = v0;
  *(float4*)&t[r][cg + 8] = v1;
  __syncthreads();
  const int jr = j0 + r;                 // dest row
  const float2 sc = rowScale[(qT << 10) + jr];
  const float inv = 1.0f / sc.y;
  unsigned int w[4];
#pragma unroll
  for (int d = 0; d < 4; d++) {
    unsigned int uu[4];
#pragma unroll
    for (int e = 0; e < 4; e++) {
      float c = __half2float(t[cg + 4 * d + e][r]);
      uu[e] = min(__float2uint_rn((c - sc.x) * inv), 255u);
    }
    w[d] = uu[0] | (uu[1] << 8) | (uu[2] << 16) | (uu[3] << 24);
  }
  *(uint4*)(dst + ((size_t)jr << 10) + i0 + cg) = make_uint4(w[0], w[1], w[2], w[3]);
}

// ---- phase 2: Sinkhorn steps. Two spill-proof variants (no b[16] array).
// Live state per lane: h[16] + uv[4](16) + rs4[4](8) + ~14 addressing -> ~55 VGPR,
// safely under the 64-VGPR cap needed for 8 blocks/CU at launch_bounds(256,8).

// min path: softmin -> min (eps < ~1e-3); direct fmax folding, single pass.
__global__ __launch_bounds__(256, 8) void sink_min(
    const unsigned char* __restrict__ C8, const float2* __restrict__ rowScale,
    const float* __restrict__ pot_cur, float* __restrict__ pot_nxt,
    float csS, float cmS) {
  const int i = blockIdx.x;
  const int x = i & 7, rr = i >> 3;
  const int q = ((rr & 7) << 3) | x;     // XCD swizzle
  const int chunk = rr >> 3;
  const int mate = ((q & 7) << 3) | (q >> 3);
  const bool diag = (mate == q);
  const float cs = diag ? csS : 0.f;
  const float cm = diag ? cmS : 1.f;
  const int wave = threadIdx.x >> 6, lane = threadIdx.x & 63;
  float h[16];
  {
    const float4* hp = (const float4*)(pot_cur + (mate << 10) + (lane << 4));
    float4 h0 = hp[0], h1 = hp[1], h2 = hp[2], h3 = hp[3];
    h[0]=h0.x; h[1]=h0.y; h[2]=h0.z; h[3]=h0.w;
    h[4]=h1.x; h[5]=h1.y; h[6]=h1.z; h[7]=h1.w;
    h[8]=h2.x; h[9]=h2.y; h[10]=h2.z; h[11]=h2.w;
    h[12]=h3.x; h[13]=h3.y; h[14]=h3.z; h[15]=h3.w;
  }
  const unsigned char* Cb = C8 + ((size_t)q << 20) + ((size_t)chunk << 15) + (lane << 4);
  const int rb = chunk << 5;
  const float2* rsB = rowScale + (q << 10) + rb + wave;

#pragma unroll
  for (int half = 0; half < 2; half++) {
    uint4 uv[4];
    float2 rs4[4];
#pragma unroll
    for (int k = 0; k < 4; k++)
      uv[k] = *(const uint4*)(Cb + ((size_t)((half << 4) + (k << 2) + wave) << 10));
#pragma unroll
    for (int k = 0; k < 4; k++)
      rs4[k] = rsB[(half << 4) + (k << 2)];
#pragma unroll
    for (int k = 0; k < 4; k++) {
      const int row = rb + (half << 4) + (k << 2) + wave;
      const float ns = -rs4[k].y;
      const unsigned int w0 = uv[k].x, w1 = uv[k].y, w2 = uv[k].z, w3 = uv[k].w;
      // 4 independent max chains for ILP
      float m0 = fmaf(ub(w0, 0),  ns, h[0]);
      float m1 = fmaf(ub(w0, 8),  ns, h[1]);
      float m2 = fmaf(ub(w0, 16), ns, h[2]);
      float m3 = fmaf(ub(w0, 24), ns, h[3]);
      m0 = fmaxf(m0, fmaf(ub(w1, 0),  ns, h[4]));
      m1 = fmaxf(m1, fmaf(ub(w1, 8),  ns, h[5]));
      m2 = fmaxf(m2, fmaf(ub(w1, 16), ns, h[6]));
      m3 = fmaxf(m3, fmaf(ub(w1, 24), ns, h[7]));
      m0 = fmaxf(m0, fmaf(ub(w2, 0),  ns, h[8]));
      m1 = fmaxf(m1, fmaf(ub(w2, 8),  ns, h[9]));
      m2 = fmaxf(m2, fmaf(ub(w2, 16), ns, h[10]));
      m3 = fmaxf(m3, fmaf(ub(w2, 24), ns, h[11]));
      m0 = fmaxf(m0, fmaf(ub(w3, 0),  ns, h[12]));
      m1 = fmaxf(m1, fmaf(ub(w3, 8),  ns, h[13]));
      m2 = fmaxf(m2, fmaf(ub(w3, 16), ns, h[14]));
      m3 = fmaxf(m3, fmaf(ub(w3, 24), ns, h[15]));
      float m = fmaxf(fmaxf(m0, m1), fmaxf(m2, m3));
      m = wredMax(m);
      if (lane == 0)
        pot_nxt[(q << 10) + row] = cs * pot_cur[(q << 10) + row] + cm * (rs4[k].x - m);
    }
  }
}

// LSE path: exact softmin; pass1 max (no storage), pass2 recompute + exp2.
__global__ __launch_bounds__(256, 8) void sink_lse(
    const unsigned char* __restrict__ C8, const float2* __restrict__ rowScale,
    const float* __restrict__ pot_cur, float* __restrict__ pot_nxt,
    float eps, float csS, float cmS) {
  const int i = blockIdx.x;
  const int x = i & 7, rr = i >> 3;
  const int q = ((rr & 7) << 3) | x;     // XCD swizzle
  const int chunk = rr >> 3;
  const int mate = ((q & 7) << 3) | (q >> 3);
  const bool diag = (mate == q);
  const float cs = diag ? csS : 0.f;
  const float cm = diag ? cmS : 1.f;
  const int wave = threadIdx.x >> 6, lane = threadIdx.x & 63;
  const float c0 = LOG2E / eps;
  const float el2 = eps * LN2;
  float h[16];
  {
    const float4* hp = (const float4*)(pot_cur + (mate << 10) + (lane << 4));
    float4 h0 = hp[0], h1 = hp[1], h2 = hp[2], h3 = hp[3];
    h[0]=h0.x*c0; h[1]=h0.y*c0; h[2]=h0.z*c0; h[3]=h0.w*c0;
    h[4]=h1.x*c0; h[5]=h1.y*c0; h[6]=h1.z*c0; h[7]=h1.w*c0;
    h[8]=h2.x*c0; h[9]=h2.y*c0; h[10]=h2.z*c0; h[11]=h2.w*c0;
    h[12]=h3.x*c0; h[13]=h3.y*c0; h[14]=h3.z*c0; h[15]=h3.w*c0;
  }
  const unsigned char* Cb = C8 + ((size_t)q << 20) + ((size_t)chunk << 15) + (lane << 4);
  const int rb = chunk << 5;
  const float2* rsB = rowScale + (q << 10) + rb + wave;

#pragma unroll
  for (int half = 0; half < 2; half++) {
    uint4 uv[4];
    float2 rs4[4];
#pragma unroll
    for (int k = 0; k < 4; k++)
      uv[k] = *(const uint4*)(Cb + ((size_t)((half << 4) + (k << 2) + wave) << 10));
#pragma unroll
    for (int k = 0; k < 4; k++)
      rs4[k] = rsB[(half << 4) + (k << 2)];
#pragma unroll
    for (int k = 0; k < 4; k++) {
      const int row = rb + (half << 4) + (k << 2) + wave;
      const float ns = (-rs4[k].y) * c0;
      const unsigned int w0 = uv[k].x, w1 = uv[k].y, w2 = uv[k].z, w3 = uv[k].w;
      // pass 1: max over fma values, 4 independent chains, nothing stored
      float m0 = fmaf(ub(w0, 0),  ns, h[0]);
      float m1 = fmaf(ub(w0, 8),  ns, h[1]);
      float m2 = fmaf(ub(w0, 16), ns, h[2]);
      float m3 = fmaf(ub(w0, 24), ns, h[3]);
      m0 = fmaxf(m0, fmaf(ub(w1, 0),  ns, h[4]));
      m1 = fmaxf(m1, fmaf(ub(w1, 8),  ns, h[5]));
      m2 = fmaxf(m2, fmaf(ub(w1, 16), ns, h[6]));
      m3 = fmaxf(m3, fmaf(ub(w1, 24), ns, h[7]));
      m0 = fmaxf(m0, fmaf(ub(w2, 0),  ns, h[8]));
      m1 = fmaxf(m1, fmaf(ub(w2, 8),  ns, h[9]));
      m2 = fmaxf(m2, fmaf(ub(w2, 16), ns, h[10]));
      m3 = fmaxf(m3, fmaf(ub(w2, 24), ns, h[11]));
      m0 = fmaxf(m0, fmaf(ub(w3, 0),  ns, h[12]));
      m1 = fmaxf(m1, fmaf(ub(w3, 8),  ns, h[13]));
      m2 = fmaxf(m2, fmaf(ub(w3, 16), ns, h[14]));
      m3 = fmaxf(m3, fmaf(ub(w3, 24), ns, h[15]));
      float m = fmaxf(fmaxf(m0, m1), fmaxf(m2, m3));
      m = wredMax(m);
      // pass 2: recompute b and accumulate exp2(b - m); 4 chains
      float s0 = exp2f(fmaf(ub(w0, 0),  ns, h[0])  - m);
      float s1 = exp2f(fmaf(ub(w0, 8),  ns, h[1])  - m);
      float s2 = exp2f(fmaf(ub(w0, 16), ns, h[2])  - m);
      float s3 = exp2f(fmaf(ub(w0, 24), ns, h[3])  - m);
      s0 += exp2f(fmaf(ub(w1, 0),  ns, h[4])  - m);
      s1 += exp2f(fmaf(ub(w1, 8),  ns, h[5])  - m);
      s2 += exp2f(fmaf(ub(w1, 16), ns, h[6])  - m);
      s3 += exp2f(fmaf(ub(w1, 24), ns, h[7])  - m);
      s0 += exp2f(fmaf(ub(w2, 0),  ns, h[8])  - m);
      s1 += exp2f(fmaf(ub(w2, 8),  ns, h[9])  - m);
      s2 += exp2f(fmaf(ub(w2, 16), ns, h[10]) - m);
      s3 += exp2f(fmaf(ub(w2, 24), ns, h[11]) - m);
      s0 += exp2f(fmaf(ub(w3, 0),  ns, h[12]) - m);
      s1 += exp2f(fmaf(ub(w3, 8),  ns, h[13]) - m);
      s2 += exp2f(fmaf(ub(w3, 16), ns, h[14]) - m);
      s3 += exp2f(fmaf(ub(w3, 24), ns, h[15]) - m);
      float ss = (s0 + s1) + (s2 + s3);
      ss = wredSum(ss);
      const float sm = rs4[k].x - fmaf(el2, m, eps * (__logf(ss) - LOG_N));
      if (lane == 0)
        pot_nxt[(q << 10) + row] = cs * pot_cur[(q << 10) + row] + cm * sm;
    }
  }
}

// ---- phase 3: losses ----
__global__ void loss_pairs(const float* __restrict__ pot, float* __restrict__ out) {
  int pb = blockIdx.x;
  int si = c_pa[pb], sj = c_pb[pb];
  const float* fv = pot + ((8 * si + sj) << 10);
  const float* gv = pot + ((8 * sj + si) << 10);
  const float* sa = pot + ((9 * si) << 10);
  const float* sb = pot + ((9 * sj) << 10);
  float acc = 0.f;
  for (int t = threadIdx.x; t < NPT; t += 256)
    acc += (fv[t] - sa[t]) + (gv[t] - sb[t]);
  acc = wredSum(acc);
  __shared__ float wsm[4];
  if ((threadIdx.x & 63) == 0) wsm[threadIdx.x >> 6] = acc;
  __syncthreads();
  if (threadIdx.x == 0) out[1 + pb] = (wsm[0] + wsm[1] + wsm[2] + wsm[3]) * (1.0f / NPT);
}

__global__ void loss_total(float* __restrict__ out) {
  int t = threadIdx.x;
  float x = (t < NPAIR) ? out[1 + t] : 0.f;
  x = wredSum(x);
  if (t == 0) out[0] = x / (float)NPAIR;
}

extern "C" void kernel_launch(void* const* d_in, const int* in_sizes, int n_in,
                              void* d_out, int out_size, void* d_ws, size_t ws_size,
                              hipStream_t stream) {
  const float* feat = (const float*)d_in[0];
  const int* sg = (const int*)d_in[1];
  float* out = (float*)d_out;
  char* ws = (char*)d_ws;

  size_t o = 0;
  __half* Ch = (__half*)(ws + o); o += (size_t)NBLK * NPT * NPT * 2;      // 72 MB (fp16 staging)
  unsigned char* C8 = (unsigned char*)(ws + o); o += (size_t)64 * NPT * NPT; // 64 MB (u8, both orientations)
  float2* rowScale = (float2*)(ws + o); o += (size_t)64 * NPT * 8;        // 512 KB
  float4* pMn = (float4*)(ws + o); o += (size_t)NPAIR * 8 * 256 * 16;     // 0.9 MB
  float4* pMx = (float4*)(ws + o); o += (size_t)NPAIR * 8 * 256 * 16;
  u16* Gh  = (u16*)(ws + o); o += (size_t)NROW * DIM * 2;                 // 4.2 MB (bf16 features)
  float* sq = (float*)(ws + o); o += (size_t)NROW * 4;
  int* idx  = (int*)(ws + o); o += (size_t)NROW * 4;
  int* cnt  = (int*)(ws + o); o += 1024;
  float* pot[2];
  pot[0] = (float*)(ws + o); o += (size_t)64 * NPT * 4;
  pot[1] = (float*)(ws + o); o += (size_t)64 * NPT * 4;

  hipMemsetAsync(cnt, 0, 1024, stream);
  hipMemsetAsync(pot[0], 0, (size_t)64 * NPT * 4, stream);   // f0=g0=s0=0

  build_idx<<<NROW / 256, 256, 0, stream>>>(sg, idx, cnt);
  gather_rows<<<NROW, 256, 0, stream>>>(feat, idx, Gh, sq);
  cost_gemm<<<NBLK * 64, 256, 0, stream>>>(Gh, sq, Ch);
  quant_row<<<NBLK * 16, 256, 0, stream>>>(Ch, C8, rowScale);
  colminmax<<<NPAIR * 8, 256, 0, stream>>>(Ch, pMn, pMx);
  colreduce<<<NPAIR, 256, 0, stream>>>(pMn, pMx, rowScale);
  quantT<<<NPAIR * 256, 256, 0, stream>>>(Ch, rowScale, C8);

  // epsilon schedule (mirrors reference trace-time logic)
  float sched[256];
  int ns = 0;
  {
    double e = 256.0;
    const double ratio = 0.9 * 0.9;
    const double tgt = 1e-4 * 1e-4;
    while (e > tgt) { sched[ns++] = (float)e; e *= ratio; }
    sched[ns++] = (float)tgt;
  }
  const float epsT = sched[ns - 1];
  const float EPS_CUT = 1e-3f;   // below this, softmin==min to within eps*log(n) ~ 7e-3

  int cur = 0;
  for (int k = 0; k < ns; k++) {
    if (sched[k] >= EPS_CUT)
      sink_lse<<<64 * 32, 256, 0, stream>>>(C8, rowScale, pot[cur], pot[1 - cur],
                                            sched[k], 0.5f, 0.5f);
    else
      sink_min<<<64 * 32, 256, 0, stream>>>(C8, rowScale, pot[cur], pot[1 - cur],
                                            0.5f, 0.5f);
    cur ^= 1;
  }
  // final extrapolation at eps_target (diag not blended); min form
  sink_min<<<64 * 32, 256, 0, stream>>>(C8, rowScale, pot[cur], pot[1 - cur],
                                        0.0f, 1.0f);
  cur ^= 1;
  loss_pairs<<<NPAIR, 256, 0, stream>>>(pot[cur], out);
  loss_total<<<1, 64, 0, stream>>>(out);
}